// Round 1
// baseline (917.363 us; speedup 1.0000x reference)
//
#include <hip/hip_runtime.h>
#include <cstddef>

#define B_ 16
#define T_ 64
#define N_ 1024
#define D_ 32
#define H_ 64
#define C_ 32
#define O_ 12

__device__ __forceinline__ float d_tanhf(float v){ float e = __expf(2.f*v); return 1.f - 2.f/(e + 1.f); }
__device__ __forceinline__ float d_sigmf(float v){ return 1.f/(1.f + __expf(-v)); }

// ---------------- K1: U[b,n,0:64]=m1, U[b,n,64:128]=m2 ----------------
__global__ __launch_bounds__(128) void k_u(const float* __restrict__ x,
    const float* __restrict__ w1, const float* __restrict__ b1,
    const float* __restrict__ w2, const float* __restrict__ b2,
    float* __restrict__ U)
{
  int row = blockIdx.x;               // b*N + n
  int b = row >> 10, n = row & (N_-1);
  int t = threadIdx.x;
  int hh = t & (H_-1), which = t >> 6;
  __shared__ float xl[D_];
  if (t < D_) xl[t] = x[(((size_t)b*T_ + (T_-1))*N_ + n)*D_ + t];
  __syncthreads();
  const float* w  = which ? w2 : w1;
  const float* bi = which ? b2 : b1;
  float acc = bi[hh];
  #pragma unroll
  for (int d = 0; d < D_; ++d) acc += xl[d] * w[d*H_ + hh];
  U[(size_t)row*128 + which*H_ + hh] = acc;
}

// ---------------- K2: adj = softmax(tanh(S)), S = m1.m2^T + m2.m1^T ----------------
// S[n,m] = sum_k U[n,k] * U[m,(k+64)&127]
#define ADJ_S 129
__global__ __launch_bounds__(512) void k_adj(const float* __restrict__ U, float* __restrict__ adj)
{
  __shared__ float Un[64*ADJ_S];      // 64 rows of U
  __shared__ float Um[128*ADJ_S];     // 128 rows of U, halves swapped
  __shared__ float rsum[64];
  int b  = blockIdx.x >> 4;
  int n0 = (blockIdx.x & 15) * 64;
  int tid = threadIdx.x;
  int tx = tid & 31, ty = tid >> 5;   // tx: m lanes, ty: 0..15 n groups
  const float* Ub = U + (size_t)b*N_*128;
  float* aout = adj + (size_t)b*N_*N_ + (size_t)n0*N_;

  for (int l = tid; l < 64*128; l += 512) {
    int r = l >> 7, k = l & 127;
    Un[r*ADJ_S + k] = Ub[(size_t)(n0 + r)*128 + k];
  }
  float rs[4] = {0.f,0.f,0.f,0.f};

  for (int mc = 0; mc < 8; ++mc) {
    int m0 = mc * 128;
    __syncthreads();
    for (int l = tid; l < 128*128; l += 512) {
      int r = l >> 7, k = l & 127;
      Um[r*ADJ_S + ((k + 64) & 127)] = Ub[(size_t)(m0 + r)*128 + k];
    }
    __syncthreads();

    float acc[4][4];
    #pragma unroll
    for (int j=0;j<4;++j){
      #pragma unroll
      for (int i=0;i<4;++i) acc[j][i]=0.f;
    }
    #pragma unroll 2
    for (int k = 0; k < 128; ++k) {
      float un[4], um[4];
      #pragma unroll
      for (int j=0;j<4;++j) un[j] = Un[(ty + 16*j)*ADJ_S + k];
      #pragma unroll
      for (int i=0;i<4;++i) um[i] = Um[(tx + 32*i)*ADJ_S + k];
      #pragma unroll
      for (int j=0;j<4;++j){
        #pragma unroll
        for (int i=0;i<4;++i) acc[j][i] += un[j]*um[i];
      }
    }
    #pragma unroll
    for (int j=0;j<4;++j) {
      int nl = ty + 16*j;
      #pragma unroll
      for (int i=0;i<4;++i) {
        int m = m0 + tx + 32*i;
        float th = d_tanhf(acc[j][i]);
        float E  = __expf(th);
        aout[(size_t)nl*N_ + m] = E;
        rs[j] += E;
      }
    }
  }
  __syncthreads();
  // reduce row sums (reuse Um)
  #pragma unroll
  for (int j=0;j<4;++j) Um[(ty + 16*j)*32 + tx] = rs[j];
  __threadfence_block();
  __syncthreads();
  if (tid < 64) {
    float s = 0.f;
    #pragma unroll
    for (int i=0;i<32;++i) s += Um[tid*32 + i];
    rsum[tid] = 1.0f / s;
  }
  __syncthreads();
  // pass 2: normalize (rows are L2-hot)
  float4* aout4 = reinterpret_cast<float4*>(aout);
  for (int l = tid; l < 64*(N_/4); l += 512) {
    int r = l >> 8;
    float sc = rsum[r];
    float4 v = aout4[l];
    v.x *= sc; v.y *= sc; v.z *= sc; v.w *= sc;
    aout4[l] = v;
  }
}

// ---------------- K3: gated dilated convs, last-position only -> h ----------------
__global__ __launch_bounds__(256,4) void k_conv(const float* __restrict__ x,
    const float* __restrict__ fw1,const float* __restrict__ fb1,const float* __restrict__ gw1,const float* __restrict__ gb1,
    const float* __restrict__ fw2,const float* __restrict__ fb2,const float* __restrict__ gw2,const float* __restrict__ gb2,
    const float* __restrict__ fw3,const float* __restrict__ fb3,const float* __restrict__ gw3,const float* __restrict__ gb3,
    float* __restrict__ h)
{
  __shared__ float xs[8][15][32];   // x[b, 49..63, n0..n0+7, :]
  __shared__ float y1[8][7][32];    // conv1 out at t=51,53,...,63
  __shared__ float y2[8][3][32];    // conv2 out at t=55,59,63
  int tid = threadIdx.x;
  int b  = blockIdx.x >> 7;
  int n0 = (blockIdx.x & 127) * 8;
  int nl = tid >> 5, d = tid & 31;
  #pragma unroll
  for (int t = 0; t < 15; ++t)
    xs[nl][t][d] = x[(((size_t)b*T_ + (49 + t))*N_ + (n0 + nl))*D_ + d];
  __syncthreads();

  int s = tid >> 5, c = tid & 31;
  // ---- conv1 (dil 1) at 7 positions
  float af[7], ag[7];
  float bf = fb1[c], bg = gb1[c];
  #pragma unroll
  for (int p=0;p<7;++p){ af[p]=bf; ag[p]=bg; }
  for (int ic = 0; ic < 32; ++ic) {
    float wf[3], wg[3];
    #pragma unroll
    for (int k=0;k<3;++k){ wf[k]=fw1[(c*32+ic)*3+k]; wg[k]=gw1[(c*32+ic)*3+k]; }
    float xv[15];
    #pragma unroll
    for (int t=0;t<15;++t) xv[t] = xs[s][t][ic];
    #pragma unroll
    for (int p=0;p<7;++p){
      #pragma unroll
      for (int k=0;k<3;++k){ af[p] += xv[2*p+k]*wf[k]; ag[p] += xv[2*p+k]*wg[k]; }
    }
  }
  #pragma unroll
  for (int p=0;p<7;++p) y1[s][p][c] = d_tanhf(af[p]) * d_sigmf(ag[p]);
  __syncthreads();

  // ---- conv2 (dil 2) at 3 positions: taps y1[2r+k]
  float af2[3], ag2[3];
  float bf2 = fb2[c], bg2 = gb2[c];
  #pragma unroll
  for (int r=0;r<3;++r){ af2[r]=bf2; ag2[r]=bg2; }
  for (int ic = 0; ic < 32; ++ic) {
    float wf[3], wg[3];
    #pragma unroll
    for (int k=0;k<3;++k){ wf[k]=fw2[(c*32+ic)*3+k]; wg[k]=gw2[(c*32+ic)*3+k]; }
    float yv[7];
    #pragma unroll
    for (int j=0;j<7;++j) yv[j] = y1[s][j][ic];
    #pragma unroll
    for (int r=0;r<3;++r){
      #pragma unroll
      for (int k=0;k<3;++k){ af2[r] += yv[2*r+k]*wf[k]; ag2[r] += yv[2*r+k]*wg[k]; }
    }
  }
  #pragma unroll
  for (int r=0;r<3;++r) y2[s][r][c] = d_tanhf(af2[r]) * d_sigmf(ag2[r]);
  __syncthreads();

  // ---- conv3 (dil 4) at last position: taps y2[k]
  float af3 = fb3[c], ag3 = gb3[c];
  for (int ic = 0; ic < 32; ++ic) {
    float wf[3], wg[3];
    #pragma unroll
    for (int k=0;k<3;++k){ wf[k]=fw3[(c*32+ic)*3+k]; wg[k]=gw3[(c*32+ic)*3+k]; }
    float yv[3];
    #pragma unroll
    for (int r=0;r<3;++r) yv[r] = y2[s][r][ic];
    #pragma unroll
    for (int k=0;k<3;++k){ af3 += yv[k]*wf[k]; ag3 += yv[k]*wg[k]; }
  }
  h[((size_t)b*N_ + n0 + s)*C_ + c] = d_tanhf(af3) * d_sigmf(ag3);
}

// ---------------- K4: z_out = 0.1 h + 0.45 z + 0.45 adj@z ----------------
__global__ __launch_bounds__(512) void k_prop(const float* __restrict__ adj, const float* __restrict__ h,
                                              const float* __restrict__ zin, float* __restrict__ zout)
{
  __shared__ float zl[N_*32];         // 128 KiB: full z for this batch
  int b  = blockIdx.x >> 4;
  int n0 = (blockIdx.x & 15) * 64;
  int tid = threadIdx.x;
  const float4* zb4 = reinterpret_cast<const float4*>(zin + (size_t)b*N_*32);
  float4* zl4 = reinterpret_cast<float4*>(zl);
  for (int l = tid; l < N_*32/4; l += 512) zl4[l] = zb4[l];
  __syncthreads();

  int c = tid & 31, ng = tid >> 5;    // ng 0..15
  const float* arow[4];
  float acc[4] = {0.f,0.f,0.f,0.f};
  #pragma unroll
  for (int j=0;j<4;++j) arow[j] = adj + ((size_t)b*N_ + n0 + ng + 16*j)*N_;

  #pragma unroll 4
  for (int m = 0; m < N_; m += 4) {
    float z0 = zl[(m+0)*32 + c];
    float z1 = zl[(m+1)*32 + c];
    float z2 = zl[(m+2)*32 + c];
    float z3 = zl[(m+3)*32 + c];
    #pragma unroll
    for (int j=0;j<4;++j) {
      float4 a = *reinterpret_cast<const float4*>(arow[j] + m);
      acc[j] += a.x*z0 + a.y*z1 + a.z*z2 + a.w*z3;
    }
  }
  #pragma unroll
  for (int j=0;j<4;++j) {
    int nl = n0 + ng + 16*j;
    size_t idx = ((size_t)b*N_ + nl)*32 + c;
    zout[idx] = 0.1f*h[idx] + 0.45f*zl[nl*32 + c] + 0.45f*acc[j];
  }
}

// ---------------- K5: out = relu(z) @ wo + bo ----------------
__global__ __launch_bounds__(256) void k_out(const float* __restrict__ z, const float* __restrict__ wo,
                                             const float* __restrict__ bo, float* __restrict__ out)
{
  int gid = blockIdx.x*256 + threadIdx.x;
  if (gid >= B_*N_*O_) return;
  int o = gid % O_; int row = gid / O_;
  const float* zr = z + (size_t)row*C_;
  float acc = bo[o];
  #pragma unroll
  for (int cc = 0; cc < C_; ++cc) acc += fmaxf(zr[cc], 0.f) * wo[cc*O_ + o];
  out[gid] = acc;
}

extern "C" void kernel_launch(void* const* d_in, const int* in_sizes, int n_in,
                              void* d_out, int out_size, void* d_ws, size_t ws_size,
                              hipStream_t stream)
{
  const float* x   = (const float*)d_in[0];
  const float* w1  = (const float*)d_in[1];
  const float* b1  = (const float*)d_in[2];
  const float* w2  = (const float*)d_in[3];
  const float* b2  = (const float*)d_in[4];
  const float* fw1 = (const float*)d_in[5];  const float* fb1 = (const float*)d_in[6];
  const float* gw1 = (const float*)d_in[7];  const float* gb1 = (const float*)d_in[8];
  const float* fw2 = (const float*)d_in[9];  const float* fb2 = (const float*)d_in[10];
  const float* gw2 = (const float*)d_in[11]; const float* gb2 = (const float*)d_in[12];
  const float* fw3 = (const float*)d_in[13]; const float* fb3 = (const float*)d_in[14];
  const float* gw3 = (const float*)d_in[15]; const float* gb3 = (const float*)d_in[16];
  const float* wo  = (const float*)d_in[17]; const float* bo  = (const float*)d_in[18];

  float* out = (float*)d_out;
  float* adj = out + (size_t)B_*N_*O_;          // second output chunk

  float* U  = (float*)d_ws;                     // [B][N][128]
  float* h  = U  + (size_t)B_*N_*128;           // [B][N][32]
  float* z0 = h  + (size_t)B_*N_*32;
  float* z1 = z0 + (size_t)B_*N_*32;

  k_u<<<B_*N_, 128, 0, stream>>>(x, w1, b1, w2, b2, U);
  k_adj<<<B_*16, 512, 0, stream>>>(U, adj);
  k_conv<<<B_*N_/8, 256, 0, stream>>>(x, fw1,fb1,gw1,gb1, fw2,fb2,gw2,gb2, fw3,fb3,gw3,gb3, h);

  const float* zi = h;
  float* zbuf[2] = {z0, z1};
  for (int it = 0; it < 10; ++it) {
    float* zo = zbuf[it & 1];
    k_prop<<<B_*16, 512, 0, stream>>>(adj, h, zi, zo);
    zi = zo;
  }
  k_out<<<(B_*N_*O_ + 255)/256, 256, 0, stream>>>(zi, wo, bo, out);
}

// Round 2
// 634.877 us; speedup vs baseline: 1.4449x; 1.4449x over previous
//
#include <hip/hip_runtime.h>
#include <cstddef>

#define B_ 16
#define T_ 64
#define N_ 1024
#define D_ 32
#define H_ 64
#define C_ 32
#define O_ 12

__device__ __forceinline__ float d_tanhf(float v){ float e = __expf(2.f*v); return 1.f - 2.f/(e + 1.f); }
__device__ __forceinline__ float d_sigmf(float v){ return 1.f/(1.f + __expf(-v)); }

// ---------------- K1: U[b,n,0:64]=m1, U[b,n,64:128]=m2 ----------------
__global__ __launch_bounds__(128) void k_u(const float* __restrict__ x,
    const float* __restrict__ w1, const float* __restrict__ b1,
    const float* __restrict__ w2, const float* __restrict__ b2,
    float* __restrict__ U)
{
  int row = blockIdx.x;               // b*N + n
  int b = row >> 10, n = row & (N_-1);
  int t = threadIdx.x;
  int hh = t & (H_-1), which = t >> 6;
  __shared__ float xl[D_];
  if (t < D_) xl[t] = x[(((size_t)b*T_ + (T_-1))*N_ + n)*D_ + t];
  __syncthreads();
  const float* w  = which ? w2 : w1;
  const float* bi = which ? b2 : b1;
  float acc = bi[hh];
  #pragma unroll
  for (int d = 0; d < D_; ++d) acc += xl[d] * w[d*H_ + hh];
  U[(size_t)row*128 + which*H_ + hh] = acc;
}

// ---------------- K2: adj = softmax(tanh(S)), S = m1.m2^T + m2.m1^T ----------------
#define ADJ_S 129
__global__ __launch_bounds__(512) void k_adj(const float* __restrict__ U, float* __restrict__ adj)
{
  __shared__ float Un[64*ADJ_S];
  __shared__ float Um[128*ADJ_S];
  __shared__ float rsum[64];
  int b  = blockIdx.x >> 4;
  int n0 = (blockIdx.x & 15) * 64;
  int tid = threadIdx.x;
  int tx = tid & 31, ty = tid >> 5;
  const float* Ub = U + (size_t)b*N_*128;
  float* aout = adj + (size_t)b*N_*N_ + (size_t)n0*N_;

  for (int l = tid; l < 64*128; l += 512) {
    int r = l >> 7, k = l & 127;
    Un[r*ADJ_S + k] = Ub[(size_t)(n0 + r)*128 + k];
  }
  float rs[4] = {0.f,0.f,0.f,0.f};

  for (int mc = 0; mc < 8; ++mc) {
    int m0 = mc * 128;
    __syncthreads();
    for (int l = tid; l < 128*128; l += 512) {
      int r = l >> 7, k = l & 127;
      Um[r*ADJ_S + ((k + 64) & 127)] = Ub[(size_t)(m0 + r)*128 + k];
    }
    __syncthreads();

    float acc[4][4];
    #pragma unroll
    for (int j=0;j<4;++j){
      #pragma unroll
      for (int i=0;i<4;++i) acc[j][i]=0.f;
    }
    #pragma unroll 2
    for (int k = 0; k < 128; ++k) {
      float un[4], um[4];
      #pragma unroll
      for (int j=0;j<4;++j) un[j] = Un[(ty + 16*j)*ADJ_S + k];
      #pragma unroll
      for (int i=0;i<4;++i) um[i] = Um[(tx + 32*i)*ADJ_S + k];
      #pragma unroll
      for (int j=0;j<4;++j){
        #pragma unroll
        for (int i=0;i<4;++i) acc[j][i] += un[j]*um[i];
      }
    }
    #pragma unroll
    for (int j=0;j<4;++j) {
      int nl = ty + 16*j;
      #pragma unroll
      for (int i=0;i<4;++i) {
        int m = m0 + tx + 32*i;
        float th = d_tanhf(acc[j][i]);
        float E  = __expf(th);
        aout[(size_t)nl*N_ + m] = E;
        rs[j] += E;
      }
    }
  }
  __syncthreads();
  #pragma unroll
  for (int j=0;j<4;++j) Um[(ty + 16*j)*32 + tx] = rs[j];
  __syncthreads();
  if (tid < 64) {
    float s = 0.f;
    #pragma unroll
    for (int i=0;i<32;++i) s += Um[tid*32 + i];
    rsum[tid] = 1.0f / s;
  }
  __syncthreads();
  float4* aout4 = reinterpret_cast<float4*>(aout);
  for (int l = tid; l < 64*(N_/4); l += 512) {
    int r = l >> 8;
    float sc = rsum[r];
    float4 v = aout4[l];
    v.x *= sc; v.y *= sc; v.z *= sc; v.w *= sc;
    aout4[l] = v;
  }
}

// ---------------- K3: gated dilated convs, last-position only -> h ----------------
// Block: 256 threads, 16 series. Thread: (sg=tid>>5 -> series pair, c=tid&31).
// Weights preloaded as float4 in ic-blocks of 8 (all indices compile-time).
__global__ __launch_bounds__(256) void k_conv(const float* __restrict__ x,
    const float* __restrict__ fw1,const float* __restrict__ fb1,const float* __restrict__ gw1,const float* __restrict__ gb1,
    const float* __restrict__ fw2,const float* __restrict__ fb2,const float* __restrict__ gw2,const float* __restrict__ gb2,
    const float* __restrict__ fw3,const float* __restrict__ fb3,const float* __restrict__ gw3,const float* __restrict__ gb3,
    float* __restrict__ h)
{
  __shared__ float xs[16][15][32];
  __shared__ float y1[16][7][32];
  __shared__ float y2[16][3][32];
  int tid = threadIdx.x;
  int b  = blockIdx.x >> 6;
  int n0 = (blockIdx.x & 63) * 16;

  // stage x[b, 49..63, n0..n0+15, :] via float4 (coalesced per t-slice)
  for (int l = tid; l < 1920; l += 256) {
    int t = l >> 7, r = l & 127;
    int nl = r >> 3, d4 = r & 7;
    float4 v = reinterpret_cast<const float4*>(x)[(((size_t)b*T_ + 49 + t)*N_ + n0 + nl)*8 + d4];
    *reinterpret_cast<float4*>(&xs[nl][t][d4*4]) = v;
  }
  __syncthreads();

  int sg = tid >> 5, c = tid & 31;
  int sA = sg*2, sB = sg*2 + 1;

  // ---- conv1 (dil 1) at 7 positions, 2 series
  float af[2][7], ag[2][7];
  {
    float bf = fb1[c], bg = gb1[c];
    #pragma unroll
    for (int ss=0; ss<2; ++ss)
      #pragma unroll
      for (int p=0;p<7;++p){ af[ss][p]=bf; ag[ss][p]=bg; }
  }
  for (int icb = 0; icb < 4; ++icb) {
    float wfl[24], wgl[24];
    #pragma unroll
    for (int q = 0; q < 6; ++q) {
      float4 a = reinterpret_cast<const float4*>(fw1)[c*24 + icb*6 + q];
      float4 g = reinterpret_cast<const float4*>(gw1)[c*24 + icb*6 + q];
      wfl[q*4+0]=a.x; wfl[q*4+1]=a.y; wfl[q*4+2]=a.z; wfl[q*4+3]=a.w;
      wgl[q*4+0]=g.x; wgl[q*4+1]=g.y; wgl[q*4+2]=g.z; wgl[q*4+3]=g.w;
    }
    #pragma unroll
    for (int ic8 = 0; ic8 < 8; ++ic8) {
      int ic = icb*8 + ic8;
      #pragma unroll
      for (int ss=0; ss<2; ++ss) {
        int s = sg*2 + ss;
        float xv[15];
        #pragma unroll
        for (int t=0;t<15;++t) xv[t] = xs[s][t][ic];
        #pragma unroll
        for (int p=0;p<7;++p){
          #pragma unroll
          for (int k=0;k<3;++k){
            af[ss][p] += xv[2*p+k]*wfl[ic8*3+k];
            ag[ss][p] += xv[2*p+k]*wgl[ic8*3+k];
          }
        }
      }
    }
  }
  #pragma unroll
  for (int ss=0; ss<2; ++ss)
    #pragma unroll
    for (int p=0;p<7;++p) y1[sg*2+ss][p][c] = d_tanhf(af[ss][p]) * d_sigmf(ag[ss][p]);
  __syncthreads();

  // ---- conv2 (dil 2) at 3 positions
  float af2[2][3], ag2[2][3];
  {
    float bf = fb2[c], bg = gb2[c];
    #pragma unroll
    for (int ss=0; ss<2; ++ss)
      #pragma unroll
      for (int r=0;r<3;++r){ af2[ss][r]=bf; ag2[ss][r]=bg; }
  }
  for (int icb = 0; icb < 4; ++icb) {
    float wfl[24], wgl[24];
    #pragma unroll
    for (int q = 0; q < 6; ++q) {
      float4 a = reinterpret_cast<const float4*>(fw2)[c*24 + icb*6 + q];
      float4 g = reinterpret_cast<const float4*>(gw2)[c*24 + icb*6 + q];
      wfl[q*4+0]=a.x; wfl[q*4+1]=a.y; wfl[q*4+2]=a.z; wfl[q*4+3]=a.w;
      wgl[q*4+0]=g.x; wgl[q*4+1]=g.y; wgl[q*4+2]=g.z; wgl[q*4+3]=g.w;
    }
    #pragma unroll
    for (int ic8 = 0; ic8 < 8; ++ic8) {
      int ic = icb*8 + ic8;
      #pragma unroll
      for (int ss=0; ss<2; ++ss) {
        int s = sg*2 + ss;
        float yv[7];
        #pragma unroll
        for (int j=0;j<7;++j) yv[j] = y1[s][j][ic];
        #pragma unroll
        for (int r=0;r<3;++r){
          #pragma unroll
          for (int k=0;k<3;++k){
            af2[ss][r] += yv[2*r+k]*wfl[ic8*3+k];
            ag2[ss][r] += yv[2*r+k]*wgl[ic8*3+k];
          }
        }
      }
    }
  }
  #pragma unroll
  for (int ss=0; ss<2; ++ss)
    #pragma unroll
    for (int r=0;r<3;++r) y2[sg*2+ss][r][c] = d_tanhf(af2[ss][r]) * d_sigmf(ag2[ss][r]);
  __syncthreads();

  // ---- conv3 (dil 4), last position only
  float af3[2], ag3[2];
  {
    float bf = fb3[c], bg = gb3[c];
    af3[0]=bf; af3[1]=bf; ag3[0]=bg; ag3[1]=bg;
  }
  for (int icb = 0; icb < 4; ++icb) {
    float wfl[24], wgl[24];
    #pragma unroll
    for (int q = 0; q < 6; ++q) {
      float4 a = reinterpret_cast<const float4*>(fw3)[c*24 + icb*6 + q];
      float4 g = reinterpret_cast<const float4*>(gw3)[c*24 + icb*6 + q];
      wfl[q*4+0]=a.x; wfl[q*4+1]=a.y; wfl[q*4+2]=a.z; wfl[q*4+3]=a.w;
      wgl[q*4+0]=g.x; wgl[q*4+1]=g.y; wgl[q*4+2]=g.z; wgl[q*4+3]=g.w;
    }
    #pragma unroll
    for (int ic8 = 0; ic8 < 8; ++ic8) {
      int ic = icb*8 + ic8;
      #pragma unroll
      for (int ss=0; ss<2; ++ss) {
        int s = sg*2 + ss;
        float yv[3];
        #pragma unroll
        for (int r=0;r<3;++r) yv[r] = y2[s][r][ic];
        #pragma unroll
        for (int k=0;k<3;++k){
          af3[ss] += yv[k]*wfl[ic8*3+k];
          ag3[ss] += yv[k]*wgl[ic8*3+k];
        }
      }
    }
  }
  #pragma unroll
  for (int ss=0; ss<2; ++ss)
    h[((size_t)b*N_ + n0 + sg*2 + ss)*C_ + c] = d_tanhf(af3[ss]) * d_sigmf(ag3[ss]);
}

// ---------------- K4: z_out = 0.1 h + 0.45 z + 0.45 adj@z  (LDS-tiled) ----------------
// Block: 256 threads = 32 rows x 8 c4. adj tile 32x128 (pad 33 f4/row), z tile 128x32.
__global__ __launch_bounds__(256) void k_prop(const float* __restrict__ adj, const float* __restrict__ h,
                                              const float* __restrict__ zin, float* __restrict__ zout)
{
  __shared__ float4 at4[32*33];
  __shared__ float4 zt4[1024];
  int b  = blockIdx.x >> 5;
  int n0 = (blockIdx.x & 31) * 32;
  int tid = threadIdx.x;
  int c4 = tid & 7, r = tid >> 3;       // r: 0..31

  const float4* adj4 = reinterpret_cast<const float4*>(adj);
  const float4* zin4 = reinterpret_cast<const float4*>(zin);
  const float4* h4   = reinterpret_cast<const float4*>(h);

  float4 acc = {0.f,0.f,0.f,0.f};

  for (int mc = 0; mc < 8; ++mc) {
    int m0 = mc * 128;
    __syncthreads();
    // stage adj tile: rows n0..n0+31, cols m0..m0+127
    for (int l = tid; l < 1024; l += 256) {
      int rr = l >> 5, cc4 = l & 31;
      at4[rr*33 + cc4] = adj4[(size_t)(b*N_ + n0 + rr)*256 + mc*32 + cc4];
    }
    // stage z tile: rows m0..m0+127 (contiguous 1024 float4s)
    for (int l = tid; l < 1024; l += 256)
      zt4[l] = zin4[(size_t)(b*N_ + m0)*8 + l];
    __syncthreads();

    #pragma unroll 4
    for (int mm4 = 0; mm4 < 32; ++mm4) {
      float4 a4 = at4[r*33 + mm4];
      float4 z0 = zt4[(mm4*4+0)*8 + c4];
      float4 z1 = zt4[(mm4*4+1)*8 + c4];
      float4 z2 = zt4[(mm4*4+2)*8 + c4];
      float4 z3 = zt4[(mm4*4+3)*8 + c4];
      acc.x += a4.x*z0.x + a4.y*z1.x + a4.z*z2.x + a4.w*z3.x;
      acc.y += a4.x*z0.y + a4.y*z1.y + a4.z*z2.y + a4.w*z3.y;
      acc.z += a4.x*z0.z + a4.y*z1.z + a4.z*z2.z + a4.w*z3.z;
      acc.w += a4.x*z0.w + a4.y*z1.w + a4.z*z2.w + a4.w*z3.w;
    }
  }

  size_t o = (size_t)(b*N_ + n0 + r)*8 + c4;
  float4 hv = h4[o], zv = zin4[o], res;
  res.x = 0.1f*hv.x + 0.45f*zv.x + 0.45f*acc.x;
  res.y = 0.1f*hv.y + 0.45f*zv.y + 0.45f*acc.y;
  res.z = 0.1f*hv.z + 0.45f*zv.z + 0.45f*acc.z;
  res.w = 0.1f*hv.w + 0.45f*zv.w + 0.45f*acc.w;
  reinterpret_cast<float4*>(zout)[o] = res;
}

// ---------------- K5: out = relu(z) @ wo + bo ----------------
__global__ __launch_bounds__(256) void k_out(const float* __restrict__ z, const float* __restrict__ wo,
                                             const float* __restrict__ bo, float* __restrict__ out)
{
  int gid = blockIdx.x*256 + threadIdx.x;
  if (gid >= B_*N_*O_) return;
  int o = gid % O_; int row = gid / O_;
  const float* zr = z + (size_t)row*C_;
  float acc = bo[o];
  #pragma unroll
  for (int cc = 0; cc < C_; ++cc) acc += fmaxf(zr[cc], 0.f) * wo[cc*O_ + o];
  out[gid] = acc;
}

extern "C" void kernel_launch(void* const* d_in, const int* in_sizes, int n_in,
                              void* d_out, int out_size, void* d_ws, size_t ws_size,
                              hipStream_t stream)
{
  const float* x   = (const float*)d_in[0];
  const float* w1  = (const float*)d_in[1];
  const float* b1  = (const float*)d_in[2];
  const float* w2  = (const float*)d_in[3];
  const float* b2  = (const float*)d_in[4];
  const float* fw1 = (const float*)d_in[5];  const float* fb1 = (const float*)d_in[6];
  const float* gw1 = (const float*)d_in[7];  const float* gb1 = (const float*)d_in[8];
  const float* fw2 = (const float*)d_in[9];  const float* fb2 = (const float*)d_in[10];
  const float* gw2 = (const float*)d_in[11]; const float* gb2 = (const float*)d_in[12];
  const float* fw3 = (const float*)d_in[13]; const float* fb3 = (const float*)d_in[14];
  const float* gw3 = (const float*)d_in[15]; const float* gb3 = (const float*)d_in[16];
  const float* wo  = (const float*)d_in[17]; const float* bo  = (const float*)d_in[18];

  float* out = (float*)d_out;
  float* adj = out + (size_t)B_*N_*O_;

  float* U  = (float*)d_ws;                     // [B][N][128]
  float* h  = U  + (size_t)B_*N_*128;           // [B][N][32]
  float* z0 = h  + (size_t)B_*N_*32;
  float* z1 = z0 + (size_t)B_*N_*32;

  k_u<<<B_*N_, 128, 0, stream>>>(x, w1, b1, w2, b2, U);
  k_adj<<<B_*16, 512, 0, stream>>>(U, adj);
  k_conv<<<B_*N_/16, 256, 0, stream>>>(x, fw1,fb1,gw1,gb1, fw2,fb2,gw2,gb2, fw3,fb3,gw3,gb3, h);

  const float* zi = h;
  float* zbuf[2] = {z0, z1};
  for (int it = 0; it < 10; ++it) {
    float* zo = zbuf[it & 1];
    k_prop<<<B_*32, 256, 0, stream>>>(adj, h, zi, zo);
    zi = zo;
  }
  k_out<<<(B_*N_*O_ + 255)/256, 256, 0, stream>>>(zi, wo, bo, out);
}